// Round 19
// baseline (137.136 us; speedup 1.0000x reference)
//
#include <hip/hip_runtime.h>

// GraphSAGE forward: lin+relu -> SAGEConv(mean)+relu -> SAGEConv(mean) -> log_softmax
// N=100000, E=1.6M, dims 128 -> 128 -> 128 -> 64.
//
// Round 19: r18's 512-thread / 8-threads-per-node gather parallelism COMBINED
// with r17's stride-128 XOR-swizzled LDS (padded stride-136 was 8-way conflict
// on 16B accesses: bank group (r+c)%8; swizzle slot^(r&7) spreads fully).
// Applied to gemm_c1c2 AND fused_front. Epilogue tiles keep stride 68.
// Rest: fused front, fp8 tables, multisplit CSR, packed stores.

#define KDIM 128
#define CH 4096             // edges per multisplit chunk (391 chunks)
#define BSH 8               // bucket = dst >> 8 (256 nodes/bucket)
#define BCAP 8192           // per-bucket LDS capacity (avg ~4100)

using bf16x8 = __attribute__((ext_vector_type(8))) short;
using f32x4  = __attribute__((ext_vector_type(4))) float;
using f32x2  = __attribute__((ext_vector_type(2))) float;

__device__ __forceinline__ unsigned short f2bf_u(float f) {
    unsigned u = __float_as_uint(f);
    u += 0x7fffu + ((u >> 16) & 1u);
    return (unsigned short)(u >> 16);
}
__device__ __forceinline__ unsigned packbf2(float a, float b) {
    return (unsigned)f2bf_u(a) | ((unsigned)f2bf_u(b) << 16);
}
__device__ __forceinline__ float bf2f(short s) {
    return __uint_as_float(((unsigned)(unsigned short)s) << 16);
}
// fp8 e4m3 (OCP) helpers
__device__ __forceinline__ unsigned char f2fp8(float v) {
    return (unsigned char)(__builtin_amdgcn_cvt_pk_fp8_f32(v, v, 0, false) & 0xff);
}
__device__ __forceinline__ void fp8x4_acc2(unsigned uu, f32x2* a) {
    a[0] += __builtin_amdgcn_cvt_pk_f32_fp8(uu, false);
    a[1] += __builtin_amdgcn_cvt_pk_f32_fp8(uu, true);
}
// exact fp8(8) -> bf16(8) dequant, packed into uint4 for ds_write_b128
__device__ __forceinline__ uint4 fp8x8_to_bf16x8(uint2 u) {
    f32x2 a0 = __builtin_amdgcn_cvt_pk_f32_fp8(u.x, false);
    f32x2 a1 = __builtin_amdgcn_cvt_pk_f32_fp8(u.x, true);
    f32x2 a2 = __builtin_amdgcn_cvt_pk_f32_fp8(u.y, false);
    f32x2 a3 = __builtin_amdgcn_cvt_pk_f32_fp8(u.y, true);
    uint4 o;
    o.x = packbf2(a0.x, a0.y); o.y = packbf2(a1.x, a1.y);
    o.z = packbf2(a2.x, a2.y); o.w = packbf2(a3.x, a3.y);
    return o;
}
// 8 bf16 (LDS) -> packed uint2 of 8 fp8
__device__ __forceinline__ uint2 bf16x8_to_fp8x8(const short* p) {
    unsigned w0 = __builtin_amdgcn_cvt_pk_fp8_f32(bf2f(p[0]), bf2f(p[1]), 0, false);
    w0 = (unsigned)__builtin_amdgcn_cvt_pk_fp8_f32(bf2f(p[2]), bf2f(p[3]), (int)w0, true);
    unsigned w1 = __builtin_amdgcn_cvt_pk_fp8_f32(bf2f(p[4]), bf2f(p[5]), 0, false);
    w1 = (unsigned)__builtin_amdgcn_cvt_pk_fp8_f32(bf2f(p[6]), bf2f(p[7]), (int)w1, true);
    return uint2{w0, w1};
}

__device__ __forceinline__ void gload_lds16(const short* g, short* l) {
    __builtin_amdgcn_global_load_lds(
        (const __attribute__((address_space(1))) unsigned int*)g,
        (__attribute__((address_space(3))) unsigned int*)l, 16, 0, 0);
}

// ---- fused front: bin_hist || pack_weights(c1/c2) || gemm_lin ----
__global__ __launch_bounds__(256) void fused_front(
    const int* __restrict__ ei, int* __restrict__ hist, int E, int nwg, int NB,
    const float* __restrict__ Wc1l, const float* __restrict__ Wc1r,
    const float* __restrict__ Wc2l, const float* __restrict__ Wc2r,
    short* __restrict__ wp,
    const float* __restrict__ X, const float* __restrict__ Wlin,
    const float* __restrict__ bias, unsigned char* __restrict__ h1q, int N)
{
    __shared__ __attribute__((aligned(16))) short xa[64 * 136];
    const int bid = blockIdx.x;
    const int t = threadIdx.x;

    if (bid < nwg) {
        // ---- bin_hist ----
        int* lh = (int*)xa;
        for (int b = t; b < NB; b += 256) lh[b] = 0;
        __syncthreads();
        const int e0 = bid * CH, e1 = min(E, e0 + CH);
        for (int e = e0 + t; e < e1; e += 256)
            atomicAdd(&lh[ei[E + e] >> BSH], 1);
        __syncthreads();
        for (int b = t; b < NB; b += 256) hist[b * nwg + bid] = lh[b];
        return;
    }
    if (bid < nwg + 192) {
        // ---- pack c1/c2 weights ----
        int idx = (bid - nwg) * 256 + t;        // 0..49151
        const float* W; short* dst; int off, ncf;
        if (idx < 16384)      { W = Wc1l; dst = wp;         off = idx;         ncf = 8; }
        else if (idx < 32768) { W = Wc1r; dst = wp + 16384; off = idx - 16384; ncf = 8; }
        else if (idx < 40960) { W = Wc2l; dst = wp + 32768; off = idx - 32768; ncf = 4; }
        else                  { W = Wc2r; dst = wp + 40960; off = idx - 40960; ncf = 4; }
        int j    = off & 7;
        int lane = (off >> 3) & 63;
        int cf   = (off >> 9) & (ncf - 1);
        int ks   = off >> ((ncf == 8) ? 12 : 11);
        int m = cf * 16 + (lane & 15);
        int k = ks * 32 + ((lane >> 4) << 3) + j;
        dst[off] = (short)f2bf_u(W[m * KDIM + k]);
        return;
    }

    // ---- gemm_lin: h1q = fp8(relu(x @ Wlin^T + b)) ----
    const int w = t >> 6, lane = t & 63;
    const int row0 = (bid - nwg - 192) * 64;
    const int cf0 = w * 2;

    bf16x8 bwA[4][2];
    #pragma unroll
    for (int ks = 0; ks < 4; ++ks)
        #pragma unroll
        for (int c = 0; c < 2; ++c) {
            const int m = (cf0 + c) * 16 + (lane & 15);
            const int kb = ks * 32 + ((lane >> 4) << 3);
            const float4 wa = *(const float4*)(Wlin + m * KDIM + kb);
            const float4 wb = *(const float4*)(Wlin + m * KDIM + kb + 4);
            bf16x8 r;
            r[0] = (short)f2bf_u(wa.x); r[1] = (short)f2bf_u(wa.y);
            r[2] = (short)f2bf_u(wa.z); r[3] = (short)f2bf_u(wa.w);
            r[4] = (short)f2bf_u(wb.x); r[5] = (short)f2bf_u(wb.y);
            r[6] = (short)f2bf_u(wb.z); r[7] = (short)f2bf_u(wb.w);
            bwA[ks][c] = r;
        }

    // stage x: LDS slot (r,s) holds global granule s^(r&7)  [stride 128]
    #pragma unroll
    for (int j = 0; j < 4; ++j) {
        const int sl = t + 256 * j;          // 0..1023
        const int r = sl >> 4, s = sl & 15;
        const int gg = s ^ (r & 7);
        const int grow = min(row0 + r, N - 1);
        const float4 f0 = *(const float4*)(X + (long)grow * KDIM + gg * 8);
        const float4 f1 = *(const float4*)(X + (long)grow * KDIM + gg * 8 + 4);
        uint4 o;
        o.x = packbf2(f0.x, f0.y); o.y = packbf2(f0.z, f0.w);
        o.z = packbf2(f1.x, f1.y); o.w = packbf2(f1.z, f1.w);
        *(uint4*)(xa + r * KDIM + s * 8) = o;
    }

    f32x4 acc[4][2];
    #pragma unroll
    for (int c = 0; c < 2; ++c) {
        const float bv = bias[(cf0 + c) * 16 + (lane & 15)];
        #pragma unroll
        for (int rf = 0; rf < 4; ++rf)
            acc[rf][c] = f32x4{bv, bv, bv, bv};
    }

    __syncthreads();

    #pragma unroll
    for (int ks = 0; ks < 4; ++ks) {
        #pragma unroll
        for (int rf = 0; rf < 4; ++rf) {
            const int rl = rf * 16 + (lane & 15);
            const int s = (ks * 4 + (lane >> 4)) ^ (rl & 7);
            const bf16x8 a = *(const bf16x8*)(xa + rl * KDIM + s * 8);
            #pragma unroll
            for (int c = 0; c < 2; ++c)
                acc[rf][c] = __builtin_amdgcn_mfma_f32_16x16x32_bf16(
                    a, bwA[ks][c], acc[rf][c], 0, 0, 0);
        }
    }

    // epilogue: stage bf16 to LDS (stride 136), then packed fp8 stores
    __syncthreads();
    #pragma unroll
    for (int rf = 0; rf < 4; ++rf)
        #pragma unroll
        for (int c = 0; c < 2; ++c)
            #pragma unroll
            for (int q = 0; q < 4; ++q) {
                const int r = rf * 16 + (lane >> 4) * 4 + q;
                const int col = (cf0 + c) * 16 + (lane & 15);
                xa[r * 136 + col] = (short)f2bf_u(fmaxf(acc[rf][c][q], 0.f));
            }
    __syncthreads();
    #pragma unroll
    for (int j = 0; j < 4; ++j) {
        const int sl = t + 256 * j;          // 0..1023
        const int r = sl >> 4, ch = sl & 15;
        const int row = row0 + r;
        if (row < N)
            *(uint2*)(h1q + (long)row * KDIM + ch * 8) =
                bf16x8_to_fp8x8(xa + r * 136 + ch * 8);
    }
}

// ---- CSR scan/scatter/sort ----

__global__ __launch_bounds__(256) void greduce(
    const int* __restrict__ in, int* __restrict__ bsum, int n)
{
    const int t = threadIdx.x;
    const int idx = blockIdx.x * 1024 + t * 4;
    int s = 0;
    if (idx + 4 <= n) {
        int4 a = *(const int4*)(in + idx);
        s = a.x + a.y + a.z + a.w;
    } else {
        #pragma unroll
        for (int k = 0; k < 4; ++k) if (idx + k < n) s += in[idx + k];
    }
    #pragma unroll
    for (int d = 1; d < 64; d <<= 1) s += __shfl_xor(s, d);
    __shared__ int ws[4];
    if ((t & 63) == 0) ws[t >> 6] = s;
    __syncthreads();
    if (t == 0) bsum[blockIdx.x] = ws[0] + ws[1] + ws[2] + ws[3];
}

__global__ __launch_bounds__(256) void scan_bsums(int* __restrict__ bsum, int nb)
{
    const int t = threadIdx.x;
    const int lane = t & 63, wid = t >> 6;
    int v = (t < nb) ? bsum[t] : 0;
    int incl = v;
    #pragma unroll
    for (int d = 1; d < 64; d <<= 1) {
        int u = __shfl_up(incl, d);
        if (lane >= d) incl += u;
    }
    __shared__ int ws[4];
    if (lane == 63) ws[wid] = incl;
    __syncthreads();
    int woff = 0;
    #pragma unroll
    for (int w = 0; w < 4; ++w) if (w < wid) woff += ws[w];
    const int excl = woff + incl - v;
    if (t <= nb) bsum[t] = excl;
}

__global__ __launch_bounds__(256) void gapply(
    int* __restrict__ io, const int* __restrict__ bsum, int n)
{
    const int t = threadIdx.x;
    const int lane = t & 63, wid = t >> 6;
    const int idx = blockIdx.x * 1024 + t * 4;
    int v[4] = {0, 0, 0, 0};
    if (idx + 4 <= n) {
        int4 a = *(const int4*)(io + idx);
        v[0] = a.x; v[1] = a.y; v[2] = a.z; v[3] = a.w;
    } else {
        #pragma unroll
        for (int k = 0; k < 4; ++k) if (idx + k < n) v[k] = io[idx + k];
    }
    const int sum = v[0] + v[1] + v[2] + v[3];
    int incl = sum;
    #pragma unroll
    for (int d = 1; d < 64; d <<= 1) {
        int u = __shfl_up(incl, d);
        if (lane >= d) incl += u;
    }
    __shared__ int ws[4];
    if (lane == 63) ws[wid] = incl;
    __syncthreads();
    int woff = 0;
    #pragma unroll
    for (int w = 0; w < 4; ++w) if (w < wid) woff += ws[w];
    int excl = bsum[blockIdx.x] + woff + (incl - sum);
    if (idx + 4 <= n) {
        int4 o;
        o.x = excl; o.y = excl + v[0]; o.z = excl + v[0] + v[1];
        o.w = excl + v[0] + v[1] + v[2];
        *(int4*)(io + idx) = o;
    } else {
        #pragma unroll
        for (int k = 0; k < 4; ++k) {
            if (idx + k < n) { io[idx + k] = excl; excl += v[k]; }
        }
    }
}

__global__ __launch_bounds__(256) void bin_scatter(
    const int* __restrict__ ei, const int* __restrict__ hist_s,
    unsigned* __restrict__ packed, int E, int nwg, int NB)
{
    __shared__ int lc[512];
    const int w = blockIdx.x, t = threadIdx.x;
    for (int b = t; b < NB; b += 256) lc[b] = hist_s[b * nwg + w];
    __syncthreads();
    const int e0 = w * CH, e1 = min(E, e0 + CH);
    for (int e = e0 + t; e < e1; e += 256) {
        const int src = ei[e];
        const int dst = ei[E + e];
        const int b = dst >> BSH;
        const int pos = atomicAdd(&lc[b], 1);
        packed[pos] = ((unsigned)(dst & 255) << 17) | (unsigned)src;
    }
}

__global__ __launch_bounds__(256) void bucket_sort(
    const unsigned* __restrict__ packed, const int* __restrict__ hist_s,
    int* __restrict__ offs, float* __restrict__ degf, int* __restrict__ perm,
    int E, int nwg, int NB, int N)
{
    __shared__ unsigned le[BCAP];
    __shared__ int lp[BCAP];
    __shared__ int lh[256], lx[256], lc[256];
    __shared__ int ws[4];
    const int b = blockIdx.x, t = threadIdx.x;
    const int bb = hist_s[b * nwg];
    const int be = (b + 1 < NB) ? hist_s[(b + 1) * nwg] : E;
    int cnt = be - bb;
    if (cnt > BCAP) cnt = BCAP;
    for (int i = t; i < cnt; i += 256) le[i] = packed[bb + i];
    lh[t] = 0;
    __syncthreads();
    for (int i = t; i < cnt; i += 256) atomicAdd(&lh[le[i] >> 17], 1);
    __syncthreads();
    const int lane = t & 63, wid = t >> 6;
    const int v = lh[t];
    int incl = v;
    #pragma unroll
    for (int d = 1; d < 64; d <<= 1) {
        int u = __shfl_up(incl, d);
        if (lane >= d) incl += u;
    }
    if (lane == 63) ws[wid] = incl;
    __syncthreads();
    int woff = 0;
    #pragma unroll
    for (int w = 0; w < 4; ++w) if (w < wid) woff += ws[w];
    const int excl = woff + incl - v;
    lx[t] = excl;
    lc[t] = excl;
    __syncthreads();
    for (int i = t; i < cnt; i += 256) {
        const unsigned p = le[i];
        const int pos = atomicAdd(&lc[p >> 17], 1);
        lp[pos] = (int)(p & 0x1FFFFu);
    }
    __syncthreads();
    for (int i = t; i < cnt; i += 256) perm[bb + i] = lp[i];
    const int node = (b << BSH) + t;
    if (node < N) {
        offs[node] = bb + lx[t];
        degf[node] = (float)v;
    }
    if (b == NB - 1 && t == 0) offs[N] = E;
}

// conv2 tail: 8-lane group per node, lane owns 8 fp8 cols of 64B g2q row.
__global__ __launch_bounds__(256) void gather_out(
    const unsigned char* __restrict__ g2q, const short* __restrict__ r2,
    const int* __restrict__ offs, const int* __restrict__ perm,
    const float* __restrict__ degf, float* __restrict__ out, int N)
{
    const int node = blockIdx.x * 32 + (threadIdx.x >> 3);
    if (node >= N) return;
    const int c = threadIdx.x & 7;           // 8B chunk within 64B fp8 row
    const int b = offs[node], e = offs[node + 1];
    f32x2 acc2[4];
    #pragma unroll
    for (int q = 0; q < 4; ++q) acc2[q] = f32x2{0.f, 0.f};
    int i = b;
    for (; i + 4 <= e; i += 4) {
        const int s0 = perm[i],     s1 = perm[i + 1];
        const int s2 = perm[i + 2], s3 = perm[i + 3];
        const uint2 u0 = *(const uint2*)(g2q + (long)s0 * 64 + c * 8);
        const uint2 u1 = *(const uint2*)(g2q + (long)s1 * 64 + c * 8);
        const uint2 u2 = *(const uint2*)(g2q + (long)s2 * 64 + c * 8);
        const uint2 u3 = *(const uint2*)(g2q + (long)s3 * 64 + c * 8);
        fp8x4_acc2(u0.x, acc2 + 0);  fp8x4_acc2(u0.y, acc2 + 2);
        fp8x4_acc2(u1.x, acc2 + 0);  fp8x4_acc2(u1.y, acc2 + 2);
        fp8x4_acc2(u2.x, acc2 + 0);  fp8x4_acc2(u2.y, acc2 + 2);
        fp8x4_acc2(u3.x, acc2 + 0);  fp8x4_acc2(u3.y, acc2 + 2);
    }
    for (; i < e; ++i) {
        const uint2 u = *(const uint2*)(g2q + (long)perm[i] * 64 + c * 8);
        fp8x4_acc2(u.x, acc2 + 0);  fp8x4_acc2(u.y, acc2 + 2);
    }
    const float inv = 1.f / fmaxf(degf[node], 1.f);
    const bf16x8 rv = *(const bf16x8*)(r2 + (long)node * 64 + c * 8);
    float v[8];
    v[0] = acc2[0].x * inv + bf2f(rv[0]);
    v[1] = acc2[0].y * inv + bf2f(rv[1]);
    v[2] = acc2[1].x * inv + bf2f(rv[2]);
    v[3] = acc2[1].y * inv + bf2f(rv[3]);
    v[4] = acc2[2].x * inv + bf2f(rv[4]);
    v[5] = acc2[2].y * inv + bf2f(rv[5]);
    v[6] = acc2[3].x * inv + bf2f(rv[6]);
    v[7] = acc2[3].y * inv + bf2f(rv[7]);
    float m = v[0];
    #pragma unroll
    for (int q = 1; q < 8; ++q) m = fmaxf(m, v[q]);
    m = fmaxf(m, __shfl_xor(m, 1));
    m = fmaxf(m, __shfl_xor(m, 2));
    m = fmaxf(m, __shfl_xor(m, 4));
    float s = 0.f;
    #pragma unroll
    for (int q = 0; q < 8; ++q) s += __expf(v[q] - m);
    s += __shfl_xor(s, 1);
    s += __shfl_xor(s, 2);
    s += __shfl_xor(s, 4);
    const float L = m + __logf(s);
    float4 oa = make_float4(v[0] - L, v[1] - L, v[2] - L, v[3] - L);
    float4 ob = make_float4(v[4] - L, v[5] - L, v[6] - L, v[7] - L);
    *(float4*)(out + (long)node * 64 + c * 8) = oa;
    *(float4*)(out + (long)node * 64 + c * 8 + 4) = ob;
}

// ---- fused gather + conv1 + conv2 GEMM (512 threads, 64-row tile) ----
//   phase 0a: A-tile = mean-gather of h1q (8 thr/node x 16 cols), XOR-swizzled
//   phase 0b: B-tile = dequant(h1q self rows), XOR-swizzled
//   phase 1:  t = relu( A @ Wl1^T + b1 + B @ Wr1^T )  (8 waves x 1 col-frag)
//   phase 2:  g2q = fp8(t @ Wl2^T), r2 = bf16(t @ Wr2^T + b2), packed stores
__global__ __launch_bounds__(512) void gemm_c1c2(
    const unsigned char* __restrict__ h1q, const int* __restrict__ offs,
    const int* __restrict__ perm, const float* __restrict__ degf,
    const short* __restrict__ wpA, const short* __restrict__ wpB,
    const short* __restrict__ wpL2, const short* __restrict__ wpR2,
    const float* __restrict__ bias1, const float* __restrict__ bias2,
    unsigned char* __restrict__ g2q, short* __restrict__ r2, int N)
{
    __shared__ __attribute__((aligned(16))) short xa[64 * KDIM];
    __shared__ __attribute__((aligned(16))) short xb[8704];  // phase1: 64*128; epilogue: 2 tiles stride 68

    const int t = threadIdx.x;
    const int w = t >> 6, lane = t & 63;
    const int row0 = blockIdx.x * 64;

    // ---- phase 0a: gather-mean into xa (8 threads/node, 16 cols each) ----
    {
        const int r = t >> 3;                // row in tile 0..63
        const int qc = t & 7;                // 16-col slice
        const int node = min(row0 + r, N - 1);
        const int b = offs[node], e = offs[node + 1];
        f32x2 a0[8];
        #pragma unroll
        for (int q = 0; q < 8; ++q) a0[q] = f32x2{0.f, 0.f};
        const unsigned char* hp = h1q + qc * 16;
        int i = b;
        for (; i + 4 <= e; i += 4) {
            const int s0 = perm[i],     s1 = perm[i + 1];
            const int s2 = perm[i + 2], s3 = perm[i + 3];
            const uint4 u0 = *(const uint4*)(hp + (long)s0 * KDIM);
            const uint4 u1 = *(const uint4*)(hp + (long)s1 * KDIM);
            const uint4 u2 = *(const uint4*)(hp + (long)s2 * KDIM);
            const uint4 u3 = *(const uint4*)(hp + (long)s3 * KDIM);
            fp8x4_acc2(u0.x, a0 + 0);  fp8x4_acc2(u0.y, a0 + 2);
            fp8x4_acc2(u0.z, a0 + 4);  fp8x4_acc2(u0.w, a0 + 6);
            fp8x4_acc2(u1.x, a0 + 0);  fp8x4_acc2(u1.y, a0 + 2);
            fp8x4_acc2(u1.z, a0 + 4);  fp8x4_acc2(u1.w, a0 + 6);
            fp8x4_acc2(u2.x, a0 + 0);  fp8x4_acc2(u2.y, a0 + 2);
            fp8x4_acc2(u2.z, a0 + 4);  fp8x4_acc2(u2.w, a0 + 6);
            fp8x4_acc2(u3.x, a0 + 0);  fp8x4_acc2(u3.y, a0 + 2);
            fp8x4_acc2(u3.z, a0 + 4);  fp8x4_acc2(u3.w, a0 + 6);
        }
        for (; i < e; ++i) {
            const uint4 u0 = *(const uint4*)(hp + (long)perm[i] * KDIM);
            fp8x4_acc2(u0.x, a0 + 0);  fp8x4_acc2(u0.y, a0 + 2);
            fp8x4_acc2(u0.z, a0 + 4);  fp8x4_acc2(u0.w, a0 + 6);
        }
        const float inv = 1.f / fmaxf(degf[node], 1.f);
        #pragma unroll
        for (int j = 0; j < 2; ++j) {
            const int slot = (qc * 2 + j) ^ (r & 7);
            uint4 o;
            o.x = packbf2(a0[4 * j + 0].x * inv, a0[4 * j + 0].y * inv);
            o.y = packbf2(a0[4 * j + 1].x * inv, a0[4 * j + 1].y * inv);
            o.z = packbf2(a0[4 * j + 2].x * inv, a0[4 * j + 2].y * inv);
            o.w = packbf2(a0[4 * j + 3].x * inv, a0[4 * j + 3].y * inv);
            *(uint4*)(xa + r * KDIM + slot * 8) = o;
        }
    }

    // ---- phase 0b: self rows -> exact bf16 dequant into xb (swizzled src) ----
    #pragma unroll
    for (int j = 0; j < 2; ++j) {
        const int sl = t + 512 * j;          // 0..1023
        const int r = sl >> 4, s = sl & 15;
        const int gg = s ^ (r & 7);
        const int grow = min(row0 + r, N - 1);
        const uint2 u = *(const uint2*)(h1q + (long)grow * KDIM + gg * 8);
        *(uint4*)(xb + r * KDIM + s * 8) = fp8x8_to_bf16x8(u);
    }

    // ---- phase 1: 8 waves x 1 col-frag ----
    bf16x8 bwA[4], bwB[4];
    #pragma unroll
    for (int ks = 0; ks < 4; ++ks) {
        bwA[ks] = *(const bf16x8*)(wpA + (((ks * 8) + w) * 64 + lane) * 8);
        bwB[ks] = *(const bf16x8*)(wpB + (((ks * 8) + w) * 64 + lane) * 8);
    }

    f32x4 acc[4];
    {
        const float bv = bias1[w * 16 + (lane & 15)];
        #pragma unroll
        for (int rf = 0; rf < 4; ++rf)
            acc[rf] = f32x4{bv, bv, bv, bv};
    }

    __syncthreads();

    #pragma unroll
    for (int ks = 0; ks < 4; ++ks) {
        #pragma unroll
        for (int rf = 0; rf < 4; ++rf) {
            const int rl = rf * 16 + (lane & 15);
            const int s = (ks * 4 + (lane >> 4)) ^ (rl & 7);
            const bf16x8 a = *(const bf16x8*)(xa + rl * KDIM + s * 8);
            acc[rf] = __builtin_amdgcn_mfma_f32_16x16x32_bf16(
                a, bwA[ks], acc[rf], 0, 0, 0);
            const bf16x8 bb = *(const bf16x8*)(xb + rl * KDIM + s * 8);
            acc[rf] = __builtin_amdgcn_mfma_f32_16x16x32_bf16(
                bb, bwB[ks], acc[rf], 0, 0, 0);
        }
    }

    // stage relu(t) into xa (bf16, XOR-swizzled layout)
    __syncthreads();
    #pragma unroll
    for (int rf = 0; rf < 4; ++rf)
        #pragma unroll
        for (int q = 0; q < 4; ++q) {
            const int r = rf * 16 + (lane >> 4) * 4 + q;
            const int col = w * 16 + (lane & 15);
            const int s = col >> 3;
            xa[r * KDIM + ((s ^ (r & 7)) << 3) + (col & 7)] =
                (short)f2bf_u(fmaxf(acc[rf][q], 0.f));
        }

    // ---- phase 2: dual 128->64 GEMM; side = w>>2, cf2 = w&3 ----
    const int side = w >> 2;
    const int cf2 = w & 3;
    const short* wp2 = side ? wpR2 : wpL2;

    bf16x8 bw2[4];
    #pragma unroll
    for (int ks = 0; ks < 4; ++ks)
        bw2[ks] = *(const bf16x8*)(wp2 + (((ks * 4) + cf2) * 64 + lane) * 8);

    f32x4 acc2[4];
    {
        const float bv = side ? bias2[cf2 * 16 + (lane & 15)] : 0.f;
        #pragma unroll
        for (int rf = 0; rf < 4; ++rf)
            acc2[rf] = f32x4{bv, bv, bv, bv};
    }

    __syncthreads();

    #pragma unroll
    for (int ks = 0; ks < 4; ++ks) {
        #pragma unroll
        for (int rf = 0; rf < 4; ++rf) {
            const int rl = rf * 16 + (lane & 15);
            const int s = (ks * 4 + (lane >> 4)) ^ (rl & 7);
            const bf16x8 a = *(const bf16x8*)(xa + rl * KDIM + s * 8);
            acc2[rf] = __builtin_amdgcn_mfma_f32_16x16x32_bf16(
                a, bw2[ks], acc2[rf], 0, 0, 0);
        }
    }

    // epilogue: stage both 64x64 tiles to xb (stride 68), packed stores
    __syncthreads();   // phase-2 reads of xb... (xb unused in phase 2; barrier orders vs phase-1 reads)
    {
        short* et = xb + (side ? 64 * 68 : 0);
        #pragma unroll
        for (int rf = 0; rf < 4; ++rf)
            #pragma unroll
            for (int q = 0; q < 4; ++q) {
                const int r = rf * 16 + (lane >> 4) * 4 + q;
                const int col = cf2 * 16 + (lane & 15);
                et[r * 68 + col] = (short)f2bf_u(acc2[rf][q]);
            }
    }
    __syncthreads();
    {
        const int r = t >> 3, ch = t & 7;    // 512 threads = 64 rows x 8 chunks
        const int row = row0 + r;
        if (row < N) {
            *(uint2*)(g2q + (long)row * 64 + ch * 8) =
                bf16x8_to_fp8x8(xb + r * 68 + ch * 8);
            *(uint4*)(r2 + (long)row * 64 + ch * 8) =
                *(const uint4*)(xb + 64 * 68 + r * 68 + ch * 8);
        }
    }
}

extern "C" void kernel_launch(void* const* d_in, const int* in_sizes, int n_in,
                              void* d_out, int out_size, void* d_ws, size_t ws_size,
                              hipStream_t stream) {
    const float* x     = (const float*)d_in[0];
    const int*   ei    = (const int*)d_in[1];
    const float* lin_W = (const float*)d_in[2];
    const float* lin_b = (const float*)d_in[3];
    const float* c1_Wl = (const float*)d_in[4];
    const float* c1_bl = (const float*)d_in[5];
    const float* c1_Wr = (const float*)d_in[6];
    const float* c2_Wl = (const float*)d_in[7];
    const float* c2_bl = (const float*)d_in[8];
    const float* c2_Wr = (const float*)d_in[9];
    float* out = (float*)d_out;

    const int N = in_sizes[0] / KDIM;
    const int E = in_sizes[1] / 2;

    short* r2   = (short*)d_ws;                       // N*64 bf16
    unsigned char* h1q = (unsigned char*)(r2 + (size_t)N * 64);  // N*128 fp8
    unsigned char* g2q = h1q + (size_t)N * KDIM;      // N*64 fp8
    short* wp   = (short*)(g2q + (size_t)N * 64);     // 49152 bf16 (c1/c2 packed)
    float* degf = (float*)(wp + 49152);               // N f32
    int* offs   = (int*)(degf + N);                   // N+1
    const int nwg = (E + CH - 1) / CH;                // 391
    const int NB  = (N + 255) >> BSH;                 // 391
    int* hist   = offs + (N + 1);                     // NB*nwg
    int* bsum   = hist + NB * nwg;                    // 256
    unsigned* packed = (unsigned*)(bsum + 256);       // E
    int* perm   = (int*)(packed + E);                 // E

    const int nb = (N + 63) / 64;
    const int nh = NB * nwg;
    const int nsb = (nh + 1023) / 1024;               // 150 < 256

    // ---- fused front: bin_hist || pack(c1/c2) || gemm_lin ----
    fused_front<<<nwg + 192 + nb, 256, 0, stream>>>(
        ei, hist, E, nwg, NB,
        c1_Wl, c1_Wr, c2_Wl, c2_Wr, wp,
        x, lin_W, lin_b, h1q, N);

    // ---- CSR scan + scatter + sort ----
    greduce<<<nsb, 256, 0, stream>>>(hist, bsum, nh);
    scan_bsums<<<1, 256, 0, stream>>>(bsum, nsb);
    gapply<<<nsb, 256, 0, stream>>>(hist, bsum, nh);
    bin_scatter<<<nwg, 256, 0, stream>>>(ei, hist, packed, E, nwg, NB);
    bucket_sort<<<NB, 256, 0, stream>>>(packed, hist, offs, degf, perm, E, nwg, NB, N);

    // fused: gather-mean (phase 0) + conv1 GEMM + conv2 dual GEMM
    gemm_c1c2<<<nb, 512, 0, stream>>>(
        h1q, offs, perm, degf,
        wp, wp + 16384, wp + 32768, wp + 40960,
        c1_bl, c2_bl, g2q, r2, N);

    // conv2 tail: out = log_softmax(gather_mean(g2q) + r2)
    gather_out<<<(N + 31) / 32, 256, 0, stream>>>(g2q, r2, offs, perm, degf, out, N);
}

// Round 20
// 135.704 us; speedup vs baseline: 1.0105x; 1.0105x over previous
//
#include <hip/hip_runtime.h>

// GraphSAGE forward: lin+relu -> SAGEConv(mean)+relu -> SAGEConv(mean) -> log_softmax
// N=100000, E=1.6M, dims 128 -> 128 -> 128 -> 64.
//
// Round 20: REVERT to round-18 (best measured, 135.8us). r19's LDS swizzle
// didn't move SQ_LDS_BANK_CONFLICT at all (2600832 both) -> conflicts are the
// 16B-access floor of the gather write pattern, not layout; swizzle only added
// VALU. Structure: fused front (bin_hist||pack||gemm_lin), multisplit CSR,
// fused gather+conv1+conv2 GEMM (512 thr, 8 thr/node gather, stride-136 LDS),
// fp8 tables with packed HW cvt, group-per-node gather_out with fast exp/log.

#define KDIM 128
#define TSTR 136            // padded LDS row stride (shorts)
#define CH 4096             // edges per multisplit chunk (391 chunks)
#define BSH 8               // bucket = dst >> 8 (256 nodes/bucket)
#define BCAP 8192           // per-bucket LDS capacity (avg ~4100)

using bf16x8 = __attribute__((ext_vector_type(8))) short;
using f32x4  = __attribute__((ext_vector_type(4))) float;
using f32x2  = __attribute__((ext_vector_type(2))) float;

__device__ __forceinline__ unsigned short f2bf_u(float f) {
    unsigned u = __float_as_uint(f);
    u += 0x7fffu + ((u >> 16) & 1u);
    return (unsigned short)(u >> 16);
}
__device__ __forceinline__ unsigned packbf2(float a, float b) {
    return (unsigned)f2bf_u(a) | ((unsigned)f2bf_u(b) << 16);
}
__device__ __forceinline__ float bf2f(short s) {
    return __uint_as_float(((unsigned)(unsigned short)s) << 16);
}
// fp8 e4m3 (OCP) helpers
__device__ __forceinline__ unsigned char f2fp8(float v) {
    return (unsigned char)(__builtin_amdgcn_cvt_pk_fp8_f32(v, v, 0, false) & 0xff);
}
__device__ __forceinline__ void fp8x4_acc2(unsigned uu, f32x2* a) {
    a[0] += __builtin_amdgcn_cvt_pk_f32_fp8(uu, false);
    a[1] += __builtin_amdgcn_cvt_pk_f32_fp8(uu, true);
}
// exact fp8(8) -> bf16(8) dequant, packed into uint4 for ds_write_b128
__device__ __forceinline__ uint4 fp8x8_to_bf16x8(uint2 u) {
    f32x2 a0 = __builtin_amdgcn_cvt_pk_f32_fp8(u.x, false);
    f32x2 a1 = __builtin_amdgcn_cvt_pk_f32_fp8(u.x, true);
    f32x2 a2 = __builtin_amdgcn_cvt_pk_f32_fp8(u.y, false);
    f32x2 a3 = __builtin_amdgcn_cvt_pk_f32_fp8(u.y, true);
    uint4 o;
    o.x = packbf2(a0.x, a0.y); o.y = packbf2(a1.x, a1.y);
    o.z = packbf2(a2.x, a2.y); o.w = packbf2(a3.x, a3.y);
    return o;
}
// 8 bf16 (LDS) -> packed uint2 of 8 fp8
__device__ __forceinline__ uint2 bf16x8_to_fp8x8(const short* p) {
    unsigned w0 = __builtin_amdgcn_cvt_pk_fp8_f32(bf2f(p[0]), bf2f(p[1]), 0, false);
    w0 = (unsigned)__builtin_amdgcn_cvt_pk_fp8_f32(bf2f(p[2]), bf2f(p[3]), (int)w0, true);
    unsigned w1 = __builtin_amdgcn_cvt_pk_fp8_f32(bf2f(p[4]), bf2f(p[5]), 0, false);
    w1 = (unsigned)__builtin_amdgcn_cvt_pk_fp8_f32(bf2f(p[6]), bf2f(p[7]), (int)w1, true);
    return uint2{w0, w1};
}

// ---- fused front: bin_hist || pack_weights(c1/c2) || gemm_lin ----
__global__ __launch_bounds__(256) void fused_front(
    const int* __restrict__ ei, int* __restrict__ hist, int E, int nwg, int NB,
    const float* __restrict__ Wc1l, const float* __restrict__ Wc1r,
    const float* __restrict__ Wc2l, const float* __restrict__ Wc2r,
    short* __restrict__ wp,
    const float* __restrict__ X, const float* __restrict__ Wlin,
    const float* __restrict__ bias, unsigned char* __restrict__ h1q, int N)
{
    __shared__ __attribute__((aligned(16))) short xa[64 * 136];
    const int bid = blockIdx.x;
    const int t = threadIdx.x;

    if (bid < nwg) {
        // ---- bin_hist ----
        int* lh = (int*)xa;
        for (int b = t; b < NB; b += 256) lh[b] = 0;
        __syncthreads();
        const int e0 = bid * CH, e1 = min(E, e0 + CH);
        for (int e = e0 + t; e < e1; e += 256)
            atomicAdd(&lh[ei[E + e] >> BSH], 1);
        __syncthreads();
        for (int b = t; b < NB; b += 256) hist[b * nwg + bid] = lh[b];
        return;
    }
    if (bid < nwg + 192) {
        // ---- pack c1/c2 weights ----
        int idx = (bid - nwg) * 256 + t;        // 0..49151
        const float* W; short* dst; int off, ncf;
        if (idx < 16384)      { W = Wc1l; dst = wp;         off = idx;         ncf = 8; }
        else if (idx < 32768) { W = Wc1r; dst = wp + 16384; off = idx - 16384; ncf = 8; }
        else if (idx < 40960) { W = Wc2l; dst = wp + 32768; off = idx - 32768; ncf = 4; }
        else                  { W = Wc2r; dst = wp + 40960; off = idx - 40960; ncf = 4; }
        int j    = off & 7;
        int lane = (off >> 3) & 63;
        int cf   = (off >> 9) & (ncf - 1);
        int ks   = off >> ((ncf == 8) ? 12 : 11);
        int m = cf * 16 + (lane & 15);
        int k = ks * 32 + ((lane >> 4) << 3) + j;
        dst[off] = (short)f2bf_u(W[m * KDIM + k]);
        return;
    }

    // ---- gemm_lin: h1q = fp8(relu(x @ Wlin^T + b)) ----
    const int w = t >> 6, lane = t & 63;
    const int row0 = (bid - nwg - 192) * 64;
    const int cf0 = w * 2;

    bf16x8 bwA[4][2];
    #pragma unroll
    for (int ks = 0; ks < 4; ++ks)
        #pragma unroll
        for (int c = 0; c < 2; ++c) {
            const int m = (cf0 + c) * 16 + (lane & 15);
            const int kb = ks * 32 + ((lane >> 4) << 3);
            const float4 wa = *(const float4*)(Wlin + m * KDIM + kb);
            const float4 wb = *(const float4*)(Wlin + m * KDIM + kb + 4);
            bf16x8 r;
            r[0] = (short)f2bf_u(wa.x); r[1] = (short)f2bf_u(wa.y);
            r[2] = (short)f2bf_u(wa.z); r[3] = (short)f2bf_u(wa.w);
            r[4] = (short)f2bf_u(wb.x); r[5] = (short)f2bf_u(wb.y);
            r[6] = (short)f2bf_u(wb.z); r[7] = (short)f2bf_u(wb.w);
            bwA[ks][c] = r;
        }

    #pragma unroll
    for (int j = 0; j < 4; ++j) {
        const int sl = t + 256 * j;          // 0..1023
        const int r = sl >> 4, s = sl & 15;
        const int grow = min(row0 + r, N - 1);
        const float4 f0 = *(const float4*)(X + (long)grow * KDIM + s * 8);
        const float4 f1 = *(const float4*)(X + (long)grow * KDIM + s * 8 + 4);
        uint4 o;
        o.x = packbf2(f0.x, f0.y); o.y = packbf2(f0.z, f0.w);
        o.z = packbf2(f1.x, f1.y); o.w = packbf2(f1.z, f1.w);
        *(uint4*)(xa + r * TSTR + s * 8) = o;
    }

    f32x4 acc[4][2];
    #pragma unroll
    for (int c = 0; c < 2; ++c) {
        const float bv = bias[(cf0 + c) * 16 + (lane & 15)];
        #pragma unroll
        for (int rf = 0; rf < 4; ++rf)
            acc[rf][c] = f32x4{bv, bv, bv, bv};
    }

    __syncthreads();

    #pragma unroll
    for (int ks = 0; ks < 4; ++ks) {
        #pragma unroll
        for (int rf = 0; rf < 4; ++rf) {
            const int rl = rf * 16 + (lane & 15);
            const int s = ks * 4 + (lane >> 4);
            const bf16x8 a = *(const bf16x8*)(xa + rl * TSTR + s * 8);
            #pragma unroll
            for (int c = 0; c < 2; ++c)
                acc[rf][c] = __builtin_amdgcn_mfma_f32_16x16x32_bf16(
                    a, bwA[ks][c], acc[rf][c], 0, 0, 0);
        }
    }

    // epilogue: stage bf16 to LDS (stride 136), then packed fp8 stores
    __syncthreads();
    #pragma unroll
    for (int rf = 0; rf < 4; ++rf)
        #pragma unroll
        for (int c = 0; c < 2; ++c)
            #pragma unroll
            for (int q = 0; q < 4; ++q) {
                const int r = rf * 16 + (lane >> 4) * 4 + q;
                const int col = (cf0 + c) * 16 + (lane & 15);
                xa[r * 136 + col] = (short)f2bf_u(fmaxf(acc[rf][c][q], 0.f));
            }
    __syncthreads();
    #pragma unroll
    for (int j = 0; j < 4; ++j) {
        const int sl = t + 256 * j;          // 0..1023
        const int r = sl >> 4, ch = sl & 15;
        const int row = row0 + r;
        if (row < N)
            *(uint2*)(h1q + (long)row * KDIM + ch * 8) =
                bf16x8_to_fp8x8(xa + r * 136 + ch * 8);
    }
}

// ---- CSR scan/scatter/sort ----

__global__ __launch_bounds__(256) void greduce(
    const int* __restrict__ in, int* __restrict__ bsum, int n)
{
    const int t = threadIdx.x;
    const int idx = blockIdx.x * 1024 + t * 4;
    int s = 0;
    if (idx + 4 <= n) {
        int4 a = *(const int4*)(in + idx);
        s = a.x + a.y + a.z + a.w;
    } else {
        #pragma unroll
        for (int k = 0; k < 4; ++k) if (idx + k < n) s += in[idx + k];
    }
    #pragma unroll
    for (int d = 1; d < 64; d <<= 1) s += __shfl_xor(s, d);
    __shared__ int ws[4];
    if ((t & 63) == 0) ws[t >> 6] = s;
    __syncthreads();
    if (t == 0) bsum[blockIdx.x] = ws[0] + ws[1] + ws[2] + ws[3];
}

__global__ __launch_bounds__(256) void scan_bsums(int* __restrict__ bsum, int nb)
{
    const int t = threadIdx.x;
    const int lane = t & 63, wid = t >> 6;
    int v = (t < nb) ? bsum[t] : 0;
    int incl = v;
    #pragma unroll
    for (int d = 1; d < 64; d <<= 1) {
        int u = __shfl_up(incl, d);
        if (lane >= d) incl += u;
    }
    __shared__ int ws[4];
    if (lane == 63) ws[wid] = incl;
    __syncthreads();
    int woff = 0;
    #pragma unroll
    for (int w = 0; w < 4; ++w) if (w < wid) woff += ws[w];
    const int excl = woff + incl - v;
    if (t <= nb) bsum[t] = excl;
}

__global__ __launch_bounds__(256) void gapply(
    int* __restrict__ io, const int* __restrict__ bsum, int n)
{
    const int t = threadIdx.x;
    const int lane = t & 63, wid = t >> 6;
    const int idx = blockIdx.x * 1024 + t * 4;
    int v[4] = {0, 0, 0, 0};
    if (idx + 4 <= n) {
        int4 a = *(const int4*)(io + idx);
        v[0] = a.x; v[1] = a.y; v[2] = a.z; v[3] = a.w;
    } else {
        #pragma unroll
        for (int k = 0; k < 4; ++k) if (idx + k < n) v[k] = io[idx + k];
    }
    const int sum = v[0] + v[1] + v[2] + v[3];
    int incl = sum;
    #pragma unroll
    for (int d = 1; d < 64; d <<= 1) {
        int u = __shfl_up(incl, d);
        if (lane >= d) incl += u;
    }
    __shared__ int ws[4];
    if (lane == 63) ws[wid] = incl;
    __syncthreads();
    int woff = 0;
    #pragma unroll
    for (int w = 0; w < 4; ++w) if (w < wid) woff += ws[w];
    int excl = bsum[blockIdx.x] + woff + (incl - sum);
    if (idx + 4 <= n) {
        int4 o;
        o.x = excl; o.y = excl + v[0]; o.z = excl + v[0] + v[1];
        o.w = excl + v[0] + v[1] + v[2];
        *(int4*)(io + idx) = o;
    } else {
        #pragma unroll
        for (int k = 0; k < 4; ++k) {
            if (idx + k < n) { io[idx + k] = excl; excl += v[k]; }
        }
    }
}

__global__ __launch_bounds__(256) void bin_scatter(
    const int* __restrict__ ei, const int* __restrict__ hist_s,
    unsigned* __restrict__ packed, int E, int nwg, int NB)
{
    __shared__ int lc[512];
    const int w = blockIdx.x, t = threadIdx.x;
    for (int b = t; b < NB; b += 256) lc[b] = hist_s[b * nwg + w];
    __syncthreads();
    const int e0 = w * CH, e1 = min(E, e0 + CH);
    for (int e = e0 + t; e < e1; e += 256) {
        const int src = ei[e];
        const int dst = ei[E + e];
        const int b = dst >> BSH;
        const int pos = atomicAdd(&lc[b], 1);
        packed[pos] = ((unsigned)(dst & 255) << 17) | (unsigned)src;
    }
}

__global__ __launch_bounds__(256) void bucket_sort(
    const unsigned* __restrict__ packed, const int* __restrict__ hist_s,
    int* __restrict__ offs, float* __restrict__ degf, int* __restrict__ perm,
    int E, int nwg, int NB, int N)
{
    __shared__ unsigned le[BCAP];
    __shared__ int lp[BCAP];
    __shared__ int lh[256], lx[256], lc[256];
    __shared__ int ws[4];
    const int b = blockIdx.x, t = threadIdx.x;
    const int bb = hist_s[b * nwg];
    const int be = (b + 1 < NB) ? hist_s[(b + 1) * nwg] : E;
    int cnt = be - bb;
    if (cnt > BCAP) cnt = BCAP;
    for (int i = t; i < cnt; i += 256) le[i] = packed[bb + i];
    lh[t] = 0;
    __syncthreads();
    for (int i = t; i < cnt; i += 256) atomicAdd(&lh[le[i] >> 17], 1);
    __syncthreads();
    const int lane = t & 63, wid = t >> 6;
    const int v = lh[t];
    int incl = v;
    #pragma unroll
    for (int d = 1; d < 64; d <<= 1) {
        int u = __shfl_up(incl, d);
        if (lane >= d) incl += u;
    }
    if (lane == 63) ws[wid] = incl;
    __syncthreads();
    int woff = 0;
    #pragma unroll
    for (int w = 0; w < 4; ++w) if (w < wid) woff += ws[w];
    const int excl = woff + incl - v;
    lx[t] = excl;
    lc[t] = excl;
    __syncthreads();
    for (int i = t; i < cnt; i += 256) {
        const unsigned p = le[i];
        const int pos = atomicAdd(&lc[p >> 17], 1);
        lp[pos] = (int)(p & 0x1FFFFu);
    }
    __syncthreads();
    for (int i = t; i < cnt; i += 256) perm[bb + i] = lp[i];
    const int node = (b << BSH) + t;
    if (node < N) {
        offs[node] = bb + lx[t];
        degf[node] = (float)v;
    }
    if (b == NB - 1 && t == 0) offs[N] = E;
}

// conv2 tail: 8-lane group per node, lane owns 8 fp8 cols of 64B g2q row.
__global__ __launch_bounds__(256) void gather_out(
    const unsigned char* __restrict__ g2q, const short* __restrict__ r2,
    const int* __restrict__ offs, const int* __restrict__ perm,
    const float* __restrict__ degf, float* __restrict__ out, int N)
{
    const int node = blockIdx.x * 32 + (threadIdx.x >> 3);
    if (node >= N) return;
    const int c = threadIdx.x & 7;           // 8B chunk within 64B fp8 row
    const int b = offs[node], e = offs[node + 1];
    f32x2 acc2[4];
    #pragma unroll
    for (int q = 0; q < 4; ++q) acc2[q] = f32x2{0.f, 0.f};
    int i = b;
    for (; i + 4 <= e; i += 4) {
        const int s0 = perm[i],     s1 = perm[i + 1];
        const int s2 = perm[i + 2], s3 = perm[i + 3];
        const uint2 u0 = *(const uint2*)(g2q + (long)s0 * 64 + c * 8);
        const uint2 u1 = *(const uint2*)(g2q + (long)s1 * 64 + c * 8);
        const uint2 u2 = *(const uint2*)(g2q + (long)s2 * 64 + c * 8);
        const uint2 u3 = *(const uint2*)(g2q + (long)s3 * 64 + c * 8);
        fp8x4_acc2(u0.x, acc2 + 0);  fp8x4_acc2(u0.y, acc2 + 2);
        fp8x4_acc2(u1.x, acc2 + 0);  fp8x4_acc2(u1.y, acc2 + 2);
        fp8x4_acc2(u2.x, acc2 + 0);  fp8x4_acc2(u2.y, acc2 + 2);
        fp8x4_acc2(u3.x, acc2 + 0);  fp8x4_acc2(u3.y, acc2 + 2);
    }
    for (; i < e; ++i) {
        const uint2 u = *(const uint2*)(g2q + (long)perm[i] * 64 + c * 8);
        fp8x4_acc2(u.x, acc2 + 0);  fp8x4_acc2(u.y, acc2 + 2);
    }
    const float inv = 1.f / fmaxf(degf[node], 1.f);
    const bf16x8 rv = *(const bf16x8*)(r2 + (long)node * 64 + c * 8);
    float v[8];
    v[0] = acc2[0].x * inv + bf2f(rv[0]);
    v[1] = acc2[0].y * inv + bf2f(rv[1]);
    v[2] = acc2[1].x * inv + bf2f(rv[2]);
    v[3] = acc2[1].y * inv + bf2f(rv[3]);
    v[4] = acc2[2].x * inv + bf2f(rv[4]);
    v[5] = acc2[2].y * inv + bf2f(rv[5]);
    v[6] = acc2[3].x * inv + bf2f(rv[6]);
    v[7] = acc2[3].y * inv + bf2f(rv[7]);
    float m = v[0];
    #pragma unroll
    for (int q = 1; q < 8; ++q) m = fmaxf(m, v[q]);
    m = fmaxf(m, __shfl_xor(m, 1));
    m = fmaxf(m, __shfl_xor(m, 2));
    m = fmaxf(m, __shfl_xor(m, 4));
    float s = 0.f;
    #pragma unroll
    for (int q = 0; q < 8; ++q) s += __expf(v[q] - m);
    s += __shfl_xor(s, 1);
    s += __shfl_xor(s, 2);
    s += __shfl_xor(s, 4);
    const float L = m + __logf(s);
    float4 oa = make_float4(v[0] - L, v[1] - L, v[2] - L, v[3] - L);
    float4 ob = make_float4(v[4] - L, v[5] - L, v[6] - L, v[7] - L);
    *(float4*)(out + (long)node * 64 + c * 8) = oa;
    *(float4*)(out + (long)node * 64 + c * 8 + 4) = ob;
}

// ---- fused gather + conv1 + conv2 GEMM (512 threads, 64-row tile) ----
//   phase 0a: A-tile = mean-gather of h1q rows (8 thr/node x 16 cols)
//   phase 0b: B-tile = dequant(h1q self rows)
//   phase 1:  t = relu( A @ Wl1^T + b1 + B @ Wr1^T )  (8 waves x 1 col-frag)
//   phase 2:  g2q = fp8(t @ Wl2^T), r2 = bf16(t @ Wr2^T + b2), packed stores
__global__ __launch_bounds__(512) void gemm_c1c2(
    const unsigned char* __restrict__ h1q, const int* __restrict__ offs,
    const int* __restrict__ perm, const float* __restrict__ degf,
    const short* __restrict__ wpA, const short* __restrict__ wpB,
    const short* __restrict__ wpL2, const short* __restrict__ wpR2,
    const float* __restrict__ bias1, const float* __restrict__ bias2,
    unsigned char* __restrict__ g2q, short* __restrict__ r2, int N)
{
    __shared__ __attribute__((aligned(16))) short xa[64 * TSTR];
    __shared__ __attribute__((aligned(16))) short xb[64 * TSTR];  // epilogue: 2 tiles stride 68

    const int t = threadIdx.x;
    const int w = t >> 6, lane = t & 63;
    const int row0 = blockIdx.x * 64;

    // ---- phase 0a: gather-mean into xa (8 threads/node, 16 cols each) ----
    {
        const int r = t >> 3;                // row in tile 0..63
        const int qc = t & 7;                // 16-col slice
        const int node = min(row0 + r, N - 1);
        const int b = offs[node], e = offs[node + 1];
        f32x2 a0[8];
        #pragma unroll
        for (int q = 0; q < 8; ++q) a0[q] = f32x2{0.f, 0.f};
        const unsigned char* hp = h1q + qc * 16;
        int i = b;
        for (; i + 4 <= e; i += 4) {
            const int s0 = perm[i],     s1 = perm[i + 1];
            const int s2 = perm[i + 2], s3 = perm[i + 3];
            const uint4 u0 = *(const uint4*)(hp + (long)s0 * KDIM);
            const uint4 u1 = *(const uint4*)(hp + (long)s1 * KDIM);
            const uint4 u2 = *(const uint4*)(hp + (long)s2 * KDIM);
            const uint4 u3 = *(const uint4*)(hp + (long)s3 * KDIM);
            fp8x4_acc2(u0.x, a0 + 0);  fp8x4_acc2(u0.y, a0 + 2);
            fp8x4_acc2(u0.z, a0 + 4);  fp8x4_acc2(u0.w, a0 + 6);
            fp8x4_acc2(u1.x, a0 + 0);  fp8x4_acc2(u1.y, a0 + 2);
            fp8x4_acc2(u1.z, a0 + 4);  fp8x4_acc2(u1.w, a0 + 6);
            fp8x4_acc2(u2.x, a0 + 0);  fp8x4_acc2(u2.y, a0 + 2);
            fp8x4_acc2(u2.z, a0 + 4);  fp8x4_acc2(u2.w, a0 + 6);
            fp8x4_acc2(u3.x, a0 + 0);  fp8x4_acc2(u3.y, a0 + 2);
            fp8x4_acc2(u3.z, a0 + 4);  fp8x4_acc2(u3.w, a0 + 6);
        }
        for (; i < e; ++i) {
            const uint4 u0 = *(const uint4*)(hp + (long)perm[i] * KDIM);
            fp8x4_acc2(u0.x, a0 + 0);  fp8x4_acc2(u0.y, a0 + 2);
            fp8x4_acc2(u0.z, a0 + 4);  fp8x4_acc2(u0.w, a0 + 6);
        }
        const float inv = 1.f / fmaxf(degf[node], 1.f);
        #pragma unroll
        for (int j = 0; j < 2; ++j) {
            uint4 o;
            o.x = packbf2(a0[4 * j + 0].x * inv, a0[4 * j + 0].y * inv);
            o.y = packbf2(a0[4 * j + 1].x * inv, a0[4 * j + 1].y * inv);
            o.z = packbf2(a0[4 * j + 2].x * inv, a0[4 * j + 2].y * inv);
            o.w = packbf2(a0[4 * j + 3].x * inv, a0[4 * j + 3].y * inv);
            *(uint4*)(xa + r * TSTR + (qc * 2 + j) * 8) = o;
        }
    }

    // ---- phase 0b: self rows (h1q fp8) -> exact bf16 dequant into xb ----
    #pragma unroll
    for (int j = 0; j < 2; ++j) {
        const int sl = t + 512 * j;          // 0..1023
        const int r = sl >> 4, s = sl & 15;
        const int grow = min(row0 + r, N - 1);
        const uint2 u = *(const uint2*)(h1q + (long)grow * KDIM + s * 8);
        *(uint4*)(xb + r * TSTR + s * 8) = fp8x8_to_bf16x8(u);
    }

    // ---- phase 1: 8 waves x 1 col-frag ----
    bf16x8 bwA[4], bwB[4];
    #pragma unroll
    for (int ks = 0; ks < 4; ++ks) {
        bwA[ks] = *(const bf16x8*)(wpA + (((ks * 8) + w) * 64 + lane) * 8);
        bwB[ks] = *(const bf16x8*)(wpB + (((ks * 8) + w) * 64 + lane) * 8);
    }

    f32x4 acc[4];
    {
        const float bv = bias1[w * 16 + (lane & 15)];
        #pragma unroll
        for (int rf = 0; rf < 4; ++rf)
            acc[rf] = f32x4{bv, bv, bv, bv};
    }

    __syncthreads();

    #pragma unroll
    for (int ks = 0; ks < 4; ++ks) {
        #pragma unroll
        for (int rf = 0; rf < 4; ++rf) {
            const int rl = rf * 16 + (lane & 15);
            const int s = ks * 4 + (lane >> 4);
            const bf16x8 a = *(const bf16x8*)(xa + rl * TSTR + s * 8);
            acc[rf] = __builtin_amdgcn_mfma_f32_16x16x32_bf16(
                a, bwA[ks], acc[rf], 0, 0, 0);
            const bf16x8 bb = *(const bf16x8*)(xb + rl * TSTR + s * 8);
            acc[rf] = __builtin_amdgcn_mfma_f32_16x16x32_bf16(
                bb, bwB[ks], acc[rf], 0, 0, 0);
        }
    }

    // stage relu(t) into xa (stride TSTR, plain layout)
    __syncthreads();
    #pragma unroll
    for (int rf = 0; rf < 4; ++rf)
        #pragma unroll
        for (int q = 0; q < 4; ++q) {
            const int r = rf * 16 + (lane >> 4) * 4 + q;
            const int col = w * 16 + (lane & 15);
            xa[r * TSTR + col] = (short)f2bf_u(fmaxf(acc[rf][q], 0.f));
        }

    // ---- phase 2: dual 128->64 GEMM; side = w>>2, cf2 = w&3 ----
    const int side = w >> 2;
    const int cf2 = w & 3;
    const short* wp2 = side ? wpR2 : wpL2;

    bf16x8 bw2[4];
    #pragma unroll
    for (int ks = 0; ks < 4; ++ks)
        bw2[ks] = *(const bf16x8*)(wp2 + (((ks * 4) + cf2) * 64 + lane) * 8);

    f32x4 acc2[4];
    {
        const float bv = side ? bias2[cf2 * 16 + (lane & 15)] : 0.f;
        #pragma unroll
        for (int rf = 0; rf < 4; ++rf)
            acc2[rf] = f32x4{bv, bv, bv, bv};
    }

    __syncthreads();

    #pragma unroll
    for (int ks = 0; ks < 4; ++ks) {
        #pragma unroll
        for (int rf = 0; rf < 4; ++rf) {
            const int rl = rf * 16 + (lane & 15);
            const int s = ks * 4 + (lane >> 4);
            const bf16x8 a = *(const bf16x8*)(xa + rl * TSTR + s * 8);
            acc2[rf] = __builtin_amdgcn_mfma_f32_16x16x32_bf16(
                a, bw2[ks], acc2[rf], 0, 0, 0);
        }
    }

    // epilogue: stage both 64x64 tiles to xb (stride 68), packed stores
    {
        short* et = xb + (side ? 64 * 68 : 0);
        #pragma unroll
        for (int rf = 0; rf < 4; ++rf)
            #pragma unroll
            for (int q = 0; q < 4; ++q) {
                const int r = rf * 16 + (lane >> 4) * 4 + q;
                const int col = cf2 * 16 + (lane & 15);
                et[r * 68 + col] = (short)f2bf_u(acc2[rf][q]);
            }
    }
    __syncthreads();
    {
        const int r = t >> 3, ch = t & 7;    // 512 threads = 64 rows x 8 chunks
        const int row = row0 + r;
        if (row < N) {
            *(uint2*)(g2q + (long)row * 64 + ch * 8) =
                bf16x8_to_fp8x8(xb + r * 68 + ch * 8);
            *(uint4*)(r2 + (long)row * 64 + ch * 8) =
                *(const uint4*)(xb + 64 * 68 + r * 68 + ch * 8);
        }
    }
}

extern "C" void kernel_launch(void* const* d_in, const int* in_sizes, int n_in,
                              void* d_out, int out_size, void* d_ws, size_t ws_size,
                              hipStream_t stream) {
    const float* x     = (const float*)d_in[0];
    const int*   ei    = (const int*)d_in[1];
    const float* lin_W = (const float*)d_in[2];
    const float* lin_b = (const float*)d_in[3];
    const float* c1_Wl = (const float*)d_in[4];
    const float* c1_bl = (const float*)d_in[5];
    const float* c1_Wr = (const float*)d_in[6];
    const float* c2_Wl = (const float*)d_in[7];
    const float* c2_bl = (const float*)d_in[8];
    const float* c2_Wr = (const float*)d_in[9];
    float* out = (float*)d_out;

    const int N = in_sizes[0] / KDIM;
    const int E = in_sizes[1] / 2;

    short* r2   = (short*)d_ws;                       // N*64 bf16
    unsigned char* h1q = (unsigned char*)(r2 + (size_t)N * 64);  // N*128 fp8
    unsigned char* g2q = h1q + (size_t)N * KDIM;      // N*64 fp8
    short* wp   = (short*)(g2q + (size_t)N * 64);     // 49152 bf16 (c1/c2 packed)
    float* degf = (float*)(wp + 49152);               // N f32
    int* offs   = (int*)(degf + N);                   // N+1
    const int nwg = (E + CH - 1) / CH;                // 391
    const int NB  = (N + 255) >> BSH;                 // 391
    int* hist   = offs + (N + 1);                     // NB*nwg
    int* bsum   = hist + NB * nwg;                    // 256
    unsigned* packed = (unsigned*)(bsum + 256);       // E
    int* perm   = (int*)(packed + E);                 // E

    const int nb = (N + 63) / 64;
    const int nh = NB * nwg;
    const int nsb = (nh + 1023) / 1024;               // 150 < 256

    // ---- fused front: bin_hist || pack(c1/c2) || gemm_lin ----
    fused_front<<<nwg + 192 + nb, 256, 0, stream>>>(
        ei, hist, E, nwg, NB,
        c1_Wl, c1_Wr, c2_Wl, c2_Wr, wp,
        x, lin_W, lin_b, h1q, N);

    // ---- CSR scan + scatter + sort ----
    greduce<<<nsb, 256, 0, stream>>>(hist, bsum, nh);
    scan_bsums<<<1, 256, 0, stream>>>(bsum, nsb);
    gapply<<<nsb, 256, 0, stream>>>(hist, bsum, nh);
    bin_scatter<<<nwg, 256, 0, stream>>>(ei, hist, packed, E, nwg, NB);
    bucket_sort<<<NB, 256, 0, stream>>>(packed, hist, offs, degf, perm, E, nwg, NB, N);

    // fused: gather-mean (phase 0) + conv1 GEMM + conv2 dual GEMM
    gemm_c1c2<<<nb, 512, 0, stream>>>(
        h1q, offs, perm, degf,
        wp, wp + 16384, wp + 32768, wp + 40960,
        c1_bl, c2_bl, g2q, r2, N);

    // conv2 tail: out = log_softmax(gather_mean(g2q) + r2)
    gather_out<<<(N + 31) / 32, 256, 0, stream>>>(g2q, r2, offs, perm, degf, out, N);
}